// Round 10
// baseline (264.630 us; speedup 1.0000x reference)
//
#include <hip/hip_runtime.h>

typedef unsigned short u16;
typedef u16  u16x8  __attribute__((ext_vector_type(8)));
typedef _Float16 f16x4 __attribute__((ext_vector_type(4)));
typedef _Float16 f16x8 __attribute__((ext_vector_type(8)));
typedef float f32x2 __attribute__((ext_vector_type(2)));
typedef float f32x4 __attribute__((ext_vector_type(4)));

#define HW 4096
#define CIN 256
#define HW32 (HW * 32)
#define L2E 1.4426950408889634f

__device__ __forceinline__ float fexp2(float x) { return __builtin_amdgcn_exp2f(x); }

// ---------------- convert x (fp32->fp16) + channel means; convert W; zero norm slots ----------------
__global__ __launch_bounds__(256) void convert_kernel(const float* x1, const float* x2, const float* x3,
        const float* W1, const float* W2, const float* W3,
        _Float16* xh, _Float16* wh, float* mean, float* maxq, float* maxk) {
    int bx = blockIdx.x; int t = threadIdx.x;
    if (bx < 1536) {
        int xi = bx >> 9, b = (bx >> 8) & 1, c = bx & 255;
        const float* src = (xi == 0 ? x1 : xi == 1 ? x2 : x3) + (size_t)(b * CIN + c) * HW;
        _Float16* dst = xh + ((size_t)((xi * 2 + b) * CIN) + c) * HW;
        float s = 0.f;
        for (int i = t; i < 1024; i += 256) {
            f32x4 v = ((const f32x4*)src)[i];
            s += v[0] + v[1] + v[2] + v[3];
            f16x4 h;
#pragma unroll
            for (int r = 0; r < 4; ++r) h[r] = (_Float16)v[r];
            ((f16x4*)dst)[i] = h;
        }
        __shared__ float red[256];
        red[t] = s; __syncthreads();
        for (int k = 128; k; k >>= 1) { if (t < k) red[t] += red[t + k]; __syncthreads(); }
        if (t == 0) mean[(xi * 2 + b) * CIN + c] = red[0] * (1.f / HW);
    } else {
        int j = bx - 1536;                 // 0..5
        if (j == 0 && t < 12) { if (t < 6) maxq[t] = 0.f; else maxk[t - 6] = 0.f; }
        int widx = j >> 1, half = j & 1;
        const float* wsrc = (widx == 0 ? W1 : widx == 1 ? W2 : W3) + half * 4096;
        _Float16* wdst = wh + widx * 8192 + half * 4096;
        for (int i = t; i < 1024; i += 256) {
            f32x4 v = ((const f32x4*)wsrc)[i];
            f16x4 h;
#pragma unroll
            for (int r = 0; r < 4; ++r) h[r] = (_Float16)v[r];
            ((f16x4*)wdst)[i] = h;
        }
    }
}

// ---- M2 partials: K-split Gram; each wave computes a 32x32 region over a 512-px chunk ----
__global__ __launch_bounds__(256) void m2_kernel(const _Float16* xh, float* Pm2) {
    int xi = blockIdx.y, b = blockIdx.z;
    int xb = xi * 2 + b;
    const _Float16* X = xh + (size_t)xb * CIN * HW;
    int bx = blockIdx.x;              // 0..127 = chunk*16 + blk
    int chunk = bx >> 4, blk = bx & 15;
    int t = threadIdx.x; int wv = t >> 6; int L = t & 63; int m = L & 15; int quad = L >> 4;
    int region = blk * 4 + wv;        // 0..63
    int r1 = (region >> 3) * 32, r2 = (region & 7) * 32;
    int p0 = chunk * 512 + quad * 8;
    const f16x8* A0 = (const f16x8*)(X + (size_t)(r1 + m) * HW + p0);
    const f16x8* A1 = (const f16x8*)(X + (size_t)(r1 + 16 + m) * HW + p0);
    const f16x8* B0 = (const f16x8*)(X + (size_t)(r2 + m) * HW + p0);
    const f16x8* B1 = (const f16x8*)(X + (size_t)(r2 + 16 + m) * HW + p0);
    f32x4 zero = {0, 0, 0, 0};
    f32x4 acc00 = zero, acc01 = zero, acc10 = zero, acc11 = zero;
#pragma unroll 4
    for (int it = 0; it < 16; ++it) {
        f16x8 a0 = A0[it * 4], a1 = A1[it * 4];
        f16x8 b0 = B0[it * 4], b1 = B1[it * 4];
        acc00 = __builtin_amdgcn_mfma_f32_16x16x32_f16(a0, b0, acc00, 0, 0, 0);
        acc01 = __builtin_amdgcn_mfma_f32_16x16x32_f16(a0, b1, acc01, 0, 0, 0);
        acc10 = __builtin_amdgcn_mfma_f32_16x16x32_f16(a1, b0, acc10, 0, 0, 0);
        acc11 = __builtin_amdgcn_mfma_f32_16x16x32_f16(a1, b1, acc11, 0, 0, 0);
    }
    float* dst = Pm2 + ((size_t)chunk * 6 + xb) * 65536;
#pragma unroll
    for (int r = 0; r < 4; ++r) {
        int row0 = (r1 + quad * 4 + r) * 256, row1 = (r1 + 16 + quad * 4 + r) * 256;
        dst[row0 + r2 + m] = acc00[r];
        dst[row0 + r2 + 16 + m] = acc01[r];
        dst[row1 + r2 + m] = acc10[r];
        dst[row1 + r2 + 16 + m] = acc11[r];
    }
}

// ---- combine M2 partials over 8 chunks ----
__global__ __launch_bounds__(256) void m2combine_kernel(const float* Pm2, float* M2) {
    size_t e = (size_t)blockIdx.x * 256 + threadIdx.x;   // 0 .. 6*65536-1
    float s = 0.f;
#pragma unroll
    for (int c = 0; c < 8; ++c) s += Pm2[(size_t)c * 6 * 65536 + e];
    M2[e] = s * (1.f / HW);
}

// ---------------- per-(x,b,o) affine params from stats (q pre-scaled by log2e) ----------------
__global__ __launch_bounds__(256) void stats_kernel(const float* M2, const float* mean,
        const float* W1, const float* W2, const float* W3,
        const float* g1, const float* g2, const float* g3,
        const float* b1, const float* b2, const float* b3, float2* afine) {
    int o = blockIdx.x; int xi = blockIdx.y; int b = blockIdx.z;
    int widx = o >> 5; int oc = o & 31;
    const float* Wp = (widx == 0 ? W1 : widx == 1 ? W2 : W3) + oc * CIN;
    const float* gp = (widx == 0 ? g1 : widx == 1 ? g2 : g3);
    const float* bp = (widx == 0 ? b1 : widx == 1 ? b2 : b3);
    int t = threadIdx.x;
    __shared__ float sW[256];
    __shared__ float red[256];
    sW[t] = Wp[t];
    __syncthreads();
    const float* m2row = M2 + ((size_t)(xi * 2 + b) * CIN + t) * CIN;
    float tv = 0.f;
    const f32x4* r4 = (const f32x4*)m2row;
#pragma unroll 4
    for (int k = 0; k < 64; ++k) {
        f32x4 mv = r4[k];
        const f32x4 wv = *(const f32x4*)&sW[k * 4];
        tv += mv[0] * wv[0] + mv[1] * wv[1] + mv[2] * wv[2] + mv[3] * wv[3];
    }
    red[t] = tv * sW[t]; __syncthreads();
    for (int k = 128; k; k >>= 1) { if (t < k) red[t] += red[t + k]; __syncthreads(); }
    float E2 = red[0]; __syncthreads();
    red[t] = sW[t] * mean[(xi * 2 + b) * CIN + t]; __syncthreads();
    for (int k = 128; k; k >>= 1) { if (t < k) red[t] += red[t + k]; __syncthreads(); }
    if (t == 0) {
        float mu = red[0];
        float var = E2 - mu * mu;
        float rsig = rsqrtf(var + 1e-5f);
        float scale = gp[oc] * rsig;
        float bias = bp[oc] - mu * scale;
        if (widx == 0) { scale *= L2E; bias *= L2E; }   // q carries log2e so S' = S*log2e
        afine[(xi * 2 + b) * 96 + o] = make_float2(scale, bias);
    }
}

// ---- conv + norm + relu: writes qT/kT (fp16), v (fp32 out), and row-norm maxima (atomics) ----
__global__ __launch_bounds__(256) void conv_kernel(const _Float16* xh, const _Float16* wh,
        const float2* afine, _Float16* qT, _Float16* kT, float* out,
        float* maxq, float* maxk) {
    int xi = blockIdx.y, b = blockIdx.z;
    const u16* xb = (const u16*)(xh + (size_t)(xi * 2 + b) * CIN * HW);
    int p0 = blockIdx.x * 64;
    __shared__ u16 lds[32 * 65 * 8];
    __shared__ float smq[4], smk[4];
    int t = threadIdx.x;
    {   // stage x[256][64] into LDS, transposed to 8-channel cells [cblk][f(p)][8c]
        int pc = t & 7, cg = t >> 3;
        u16x8 a[8];
#pragma unroll
        for (int r = 0; r < 8; ++r)
            a[r] = *(const u16x8*)(xb + (size_t)(cg * 8 + r) * HW + p0 + pc * 8);
#pragma unroll
        for (int i = 0; i < 8; ++i) {
            u16x8 d;
#pragma unroll
            for (int r = 0; r < 8; ++r) d[r] = a[r][i];
            int p = pc * 8 + i; int fp = p ^ (p >> 3);
            *(u16x8*)&lds[(cg * 65 + fp) * 8] = d;
        }
    }
    __syncthreads();
    int wv = t >> 6, L = t & 63, m = L & 15, quad = L >> 4;
    int pw0 = wv * 16;
    f16x8 af[8];
    {
        int p = pw0 + m; int fp = p ^ (p >> 3);
#pragma unroll
        for (int k = 0; k < 8; ++k)
            af[k] = *(const f16x8*)&lds[((k * 4 + quad) * 65 + fp) * 8];
    }
    int xb2 = xi * 2 + b;
    float sqq[4] = {0, 0, 0, 0}, sqk[4] = {0, 0, 0, 0};
    for (int ot = 0; ot < 6; ++ot) {
        int o0 = ot * 16; int widx = ot >> 1;
        int o_col = o0 + m;                         // global output channel 0..95
        f32x4 acc = {0, 0, 0, 0};
#pragma unroll
        for (int k = 0; k < 8; ++k) {
            f16x8 bfr = *(const f16x8*)(wh + (size_t)o_col * CIN + k * 32 + quad * 8);
            acc = __builtin_amdgcn_mfma_f32_16x16x32_f16(af[k], bfr, acc, 0, 0, 0);
        }
        float2 afv = afine[xb2 * 96 + o_col];
        f32x4 vals;
#pragma unroll
        for (int r = 0; r < 4; ++r) {
            float v = acc[r] * afv.x + afv.y;
            vals[r] = v > 0.f ? v : 0.f;
        }
        int prow = p0 + pw0 + quad * 4;
        if (widx < 2) {
            _Float16* dst = (widx == 0 ? qT : kT) + (size_t)xb2 * HW32;
            int cc = (o0 & 31) + m;
#pragma unroll
            for (int r = 0; r < 4; ++r)
                dst[(size_t)(prow + r) * 32 + cc] = (_Float16)vals[r];
            if (widx == 0) {
#pragma unroll
                for (int r = 0; r < 4; ++r) sqq[r] += vals[r] * vals[r];
            } else {
#pragma unroll
                for (int r = 0; r < 4; ++r) sqk[r] += vals[r] * vals[r];
            }
        } else {
            float* dst = out + (size_t)(5 + xi) * 262144 + (size_t)b * 131072 + (size_t)(o_col - 64) * HW + prow;
            *(f32x4*)dst = vals;    // fp32 output, 4 consecutive pixels
        }
    }
    // row-norm^2 reduce over 16 channel-lanes, then wave/block max, one atomic per block
#pragma unroll
    for (int msk = 1; msk <= 8; msk <<= 1) {
#pragma unroll
        for (int r = 0; r < 4; ++r) {
            sqq[r] += __shfl_xor(sqq[r], msk);
            sqk[r] += __shfl_xor(sqk[r], msk);
        }
    }
    float nq = fmaxf(fmaxf(sqq[0], sqq[1]), fmaxf(sqq[2], sqq[3]));
    float nk = fmaxf(fmaxf(sqk[0], sqk[1]), fmaxf(sqk[2], sqk[3]));
    nq = fmaxf(nq, __shfl_xor(nq, 16)); nq = fmaxf(nq, __shfl_xor(nq, 32));
    nk = fmaxf(nk, __shfl_xor(nk, 16)); nk = fmaxf(nk, __shfl_xor(nk, 32));
    if (L == 0) { smq[wv] = nq; smk[wv] = nk; }
    __syncthreads();
    if (t == 0) {
        float bq = fmaxf(fmaxf(smq[0], smq[1]), fmaxf(smq[2], smq[3]));
        float bk = fmaxf(fmaxf(smk[0], smk[1]), fmaxf(smk[2], smk[3]));
        atomicMax((unsigned*)&maxq[xb2], __float_as_uint(bq));   // nonneg floats: uint order == float order
        atomicMax((unsigned*)&maxk[xb2], __float_as_uint(bk));
    }
}

// ---- Z-sweep (single pass, constant shift): per-chunk partial Z sums ----
__global__ __launch_bounds__(256) void zsweep_kernel(const _Float16* qT, const _Float16* kT,
        const float* maxq, const float* maxk, float* Pz) {
    const int qxA[5] = {0, 1, 1, 2, 0};   // mats: A12 A21 A23 A32 A13
    const int kxA[5] = {1, 0, 2, 1, 2};
    int mat = blockIdx.y, b = blockIdx.z;
    const _Float16* qb = qT + (size_t)(qxA[mat] * 2 + b) * HW32;
    const _Float16* kb = kT + (size_t)(kxA[mat] * 2 + b) * HW32;
    float Cg = sqrtf(maxq[qxA[mat] * 2 + b]) * sqrtf(maxk[kxA[mat] * 2 + b]);  // log2-domain (q scaled by L2E)
    int bx = blockIdx.x;                 // 16 qblk x 16 jc
    int jc = bx & 15, qblk = bx >> 4;
    int t = threadIdx.x; int wv = t >> 6; int L = t & 63; int m = L & 15; int quad = L >> 4;
    int i0 = qblk * 256 + wv * 64;       // wave covers 64 q rows (4 tiles)
    f16x8 a[4];
#pragma unroll
    for (int tt = 0; tt < 4; ++tt)
        a[tt] = *(const f16x8*)(qb + (size_t)(i0 + tt * 16 + m) * 32 + quad * 8);
    const f16x8* kp = (const f16x8*)(kb + m * 32 + quad * 8) + (size_t)jc * (16 * 64);
    f32x4 negC = {-Cg, -Cg, -Cg, -Cg};
    f32x4 zero = {0.f, 0.f, 0.f, 0.f};
    f32x4 z[4] = {zero, zero, zero, zero};
#pragma unroll 4
    for (int j = 0; j < 16; ++j) {
        f16x8 bf = kp[j * 64];
#pragma unroll
        for (int tt = 0; tt < 4; ++tt) {
            f32x4 d = __builtin_amdgcn_mfma_f32_16x16x32_f16(a[tt], bf, negC, 0, 0, 0);
            f32x4 e = {fexp2(d[0]), fexp2(d[1]), fexp2(d[2]), fexp2(d[3])};
            z[tt] = z[tt] + e;           // vector add -> v_pk_add_f32
        }
    }
#pragma unroll
    for (int tt = 0; tt < 4; ++tt)
#pragma unroll
        for (int msk = 1; msk <= 8; msk <<= 1) {
            z[tt][0] += __shfl_xor(z[tt][0], msk); z[tt][1] += __shfl_xor(z[tt][1], msk);
            z[tt][2] += __shfl_xor(z[tt][2], msk); z[tt][3] += __shfl_xor(z[tt][3], msk);
        }
    if (m == 0) {
        int mb = mat * 2 + b;
#pragma unroll
        for (int tt = 0; tt < 4; ++tt) {
            int row = i0 + tt * 16 + quad * 4;
#pragma unroll
            for (int r = 0; r < 4; ++r)
                Pz[((size_t)mb * 16 + jc) * HW + row + r] = z[tt][r];
        }
    }
}

// ---- pass2, i-chunked, 4 j-tiles/wave; prologue builds its own weights from Pz + partials ----
struct PCfg {
    const _Float16* qb; const _Float16* kb;   // bases covering 2 batches
    const float* mq; const float* mk;         // per-batch shift factors (squared norms)
    const float* PzR;                         // Pz partials for THIS sweep's own mat (+b*16*HW inside)
    const float2* w1src;                      // partials for w.x multiplier (null -> w.x = rz)
    const float2* w2src;                      // partials for w.y multiplier (null -> single-weight)
    float2* Pp;                               // [(ic*2+b)*HW + j]
    int nit;                                  // i-iters per chunk (chunk = nit*16 rows)
    int ic1, comp1, ic2, comp2;               // chunk counts + component (0=.x,1=.y)
};

__global__ __launch_bounds__(256) void pass2p_kernel(PCfg c0, PCfg c1) {
    PCfg c = (blockIdx.y == 0) ? c0 : c1;
    int b = blockIdx.z;
    int bx = blockIdx.x; int jb = bx & 15; int ic = bx >> 4;
    const _Float16* qb = c.qb + (size_t)b * HW32;
    const _Float16* kb = c.kb + (size_t)b * HW32;
    float Cg = sqrtf(c.mq[b]) * sqrtf(c.mk[b]);
    int t = threadIdx.x; int wv = t >> 6; int L = t & 63; int m = L & 15; int quad = L >> 4;
    int ibase = ic * (c.nit * 16);
    int rows = c.nit * 16;                    // 128 or 256
    __shared__ float2 wlds[256];
    {   // prologue: weights for this block's i-rows (identical arithmetic to old prep kernels)
        for (int r = t; r < rows; r += 256) {
            int i = ibase + r;
            const float* pz = c.PzR + (size_t)b * (16 * HW) + i;
            float Z = 0.f;
#pragma unroll
            for (int cc = 0; cc < 16; ++cc) Z += pz[cc * HW];
            float rz = 1.0f / Z;
            float wx, wy = 0.f;
            if (c.w1src) {
                float s = 0.f;
                for (int cc = 0; cc < c.ic1; ++cc) {
                    float2 p = c.w1src[((size_t)cc * 2 + b) * HW + i];
                    s += c.comp1 ? p.y : p.x;
                }
                wx = s * rz;
            } else wx = rz;
            if (c.w2src) {
                float s = 0.f;
                for (int cc = 0; cc < c.ic2; ++cc) {
                    float2 p = c.w2src[((size_t)cc * 2 + b) * HW + i];
                    s += c.comp2 ? p.y : p.x;
                }
                wy = s * rz;
            }
            wlds[r] = make_float2(wx, wy);
        }
    }
    __syncthreads();
    int j0 = jb * 256 + wv * 64;         // wave covers 64 j columns (4 tiles)
    f16x8 bf[4];
#pragma unroll
    for (int tt = 0; tt < 4; ++tt)
        bf[tt] = *(const f16x8*)(kb + (size_t)(j0 + tt * 16 + m) * 32 + quad * 8);
    f32x4 negC = {-Cg, -Cg, -Cg, -Cg};
    f32x2 acc[4] = {{0, 0}, {0, 0}, {0, 0}, {0, 0}};
    int dual = (c.w2src != nullptr);
    if (dual) {
#pragma unroll 4
        for (int it = 0; it < c.nit; ++it) {
            int i0 = ibase + it * 16;
            f16x8 av = *(const f16x8*)(qb + (size_t)(i0 + m) * 32 + quad * 8);
            const float2* wr = &wlds[it * 16 + quad * 4];
            f32x2 w0 = {wr[0].x, wr[0].y}, w1 = {wr[1].x, wr[1].y};
            f32x2 w2 = {wr[2].x, wr[2].y}, w3 = {wr[3].x, wr[3].y};
#pragma unroll
            for (int tt = 0; tt < 4; ++tt) {
                f32x4 d = __builtin_amdgcn_mfma_f32_16x16x32_f16(av, bf[tt], negC, 0, 0, 0);
                float e0 = fexp2(d[0]), e1 = fexp2(d[1]), e2 = fexp2(d[2]), e3 = fexp2(d[3]);
                acc[tt] += (f32x2){e0, e0} * w0;   // v_pk_fma_f32
                acc[tt] += (f32x2){e1, e1} * w1;
                acc[tt] += (f32x2){e2, e2} * w2;
                acc[tt] += (f32x2){e3, e3} * w3;
            }
        }
    } else {
#pragma unroll 4
        for (int it = 0; it < c.nit; ++it) {
            int i0 = ibase + it * 16;
            f16x8 av = *(const f16x8*)(qb + (size_t)(i0 + m) * 32 + quad * 8);
            const float2* wr = &wlds[it * 16 + quad * 4];
            float w0 = wr[0].x, w1 = wr[1].x, w2 = wr[2].x, w3 = wr[3].x;
#pragma unroll
            for (int tt = 0; tt < 4; ++tt) {
                f32x4 d = __builtin_amdgcn_mfma_f32_16x16x32_f16(av, bf[tt], negC, 0, 0, 0);
                float e0 = fexp2(d[0]), e1 = fexp2(d[1]), e2 = fexp2(d[2]), e3 = fexp2(d[3]);
                acc[tt][0] += e0 * w0 + e1 * w1 + e2 * w2 + e3 * w3;
            }
        }
    }
#pragma unroll
    for (int tt = 0; tt < 4; ++tt) {
        acc[tt][0] += __shfl_xor(acc[tt][0], 16); acc[tt][0] += __shfl_xor(acc[tt][0], 32);
        acc[tt][1] += __shfl_xor(acc[tt][1], 16); acc[tt][1] += __shfl_xor(acc[tt][1], 32);
    }
    if (quad == 0) {
        float2* dst = c.Pp + ((size_t)ic * 2 + b) * HW;
#pragma unroll
        for (int tt = 0; tt < 4; ++tt)
            dst[j0 + tt * 16 + m] = make_float2(acc[tt][0], acc[tt][1]);
    }
}

// ---- bcast: sum partials for the 5 output vectors, broadcast to fp32 [b,32,hw] ----
__global__ __launch_bounds__(256) void bcast_kernel(const float2* PpA2, const float2* PpB,
        const float2* PpC, const float2* PpD, float* out) {
    int bx = blockIdx.x;              // 0..159: (s*2+b)*16 + jstrip
    int sb = bx >> 4; int s = sb >> 1; int b = sb & 1; int js = bx & 15;
    int j = js * 256 + threadIdx.x;
    float v = 0.f;
    if (s == 0)      { for (int ic = 0; ic < 32; ++ic) v += PpD[((size_t)ic * 2 + b) * HW + j].x; }
    else if (s == 1) { for (int ic = 0; ic < 32; ++ic) v += PpD[((size_t)ic * 2 + b) * HW + j].y; }
    else if (s == 2) { for (int ic = 0; ic < 32; ++ic) v += PpC[((size_t)ic * 2 + b) * HW + j].x; }
    else if (s == 3) { for (int ic = 0; ic < 32; ++ic) v += PpB[((size_t)ic * 2 + b) * HW + j].y; }
    else             { for (int ic = 0; ic < 16; ++ic) v += PpA2[((size_t)ic * 2 + b) * HW + j].x; }
    float* dst = out + ((size_t)(s * 2 + b) * 32) * HW + j;
#pragma unroll
    for (int c = 0; c < 32; ++c) dst[(size_t)c * HW] = v;
}

extern "C" void kernel_launch(void* const* d_in, const int* in_sizes, int n_in,
                              void* d_out, int out_size, void* d_ws, size_t ws_size,
                              hipStream_t stream) {
    (void)in_sizes; (void)n_in; (void)out_size; (void)ws_size;
    const float* x1 = (const float*)d_in[0];
    const float* x2 = (const float*)d_in[1];
    const float* x3 = (const float*)d_in[2];
    const float* W1 = (const float*)d_in[3];
    const float* g1 = (const float*)d_in[4];
    const float* b1 = (const float*)d_in[5];
    const float* W2 = (const float*)d_in[6];
    const float* g2 = (const float*)d_in[7];
    const float* b2 = (const float*)d_in[8];
    const float* W3 = (const float*)d_in[9];
    const float* g3 = (const float*)d_in[10];
    const float* b3 = (const float*)d_in[11];
    float* out = (float*)d_out;      // reference outputs are float32

    char* w = (char*)d_ws;
    _Float16* xh    = (_Float16*)(w);                    // 12,582,912
    _Float16* wh    = (_Float16*)(w + 12582912);         //     49,152
    float*    mean  = (float*)(w + 12632064);            //      6,144
    float*    M2    = (float*)(w + 12638208);            //  1,572,864
    float2*   afine = (float2*)(w + 14211072);           //      4,608
    _Float16* qT    = (_Float16*)(w + 14215680);         //  1,572,864
    _Float16* kT    = (_Float16*)(w + 15788544);         //  1,572,864
    float*    maxq  = (float*)(w + 17525248);            //         64 (squared norms)
    float*    maxk  = (float*)(w + 17525312);            //         64
    float*    Pz    = (float*)(w + 18213376);            //  2,621,440 (10 mb x 16 chunks x HW)
    float2*   PpA   = (float2*)(w + 23456256);           //  2,097,152 (A12: 16 ch; A13: 16 ch)
    float2*   PpB   = (float2*)(w + 25553408);           //  2,097,152
    float2*   PpC   = (float2*)(w + 27650560);           //  2,097,152
    float2*   PpD   = (float2*)(w + 29747712);           //  2,097,152
    // Pm2 overlays Pz/PpA/PpB/PpC (disjoint lifetime: consumed by m2combine before zsweep runs)
    float*    Pm2   = (float*)(w + 18213376);            // 12,582,912 (8 chunks x 6 x 256x256 f32)
    float2*   PpA2  = PpA + 16 * 2 * HW;                 // A13 partial region

    hipLaunchKernelGGL(convert_kernel, dim3(1542), dim3(256), 0, stream,
                       x1, x2, x3, W1, W2, W3, xh, wh, mean, maxq, maxk);
    hipLaunchKernelGGL(m2_kernel, dim3(128, 3, 2), dim3(256), 0, stream, xh, Pm2);
    hipLaunchKernelGGL(m2combine_kernel, dim3(1536), dim3(256), 0, stream, Pm2, M2);
    hipLaunchKernelGGL(stats_kernel, dim3(96, 3, 2), dim3(256), 0, stream,
                       M2, mean, W1, W2, W3, g1, g2, g3, b1, b2, b3, afine);
    hipLaunchKernelGGL(conv_kernel, dim3(64, 3, 2), dim3(256), 0, stream,
                       xh, wh, afine, qT, kT, out, maxq, maxk);
    hipLaunchKernelGGL(zsweep_kernel, dim3(256, 5, 2), dim3(256), 0, stream, qT, kT, maxq, maxk, Pz);

    // mats: 0:A12(q1,k2) 1:A21(q2,k1) 2:A23(q2,k3) 3:A32(q3,k2) 4:A13(q1,k3)
    // A-pair: A12 (w={rz}) and A13 (w={rz}); IC=16 (nit=16), single-weight
    PCfg cA0 = { qT + 0 * 2 * HW32, kT + 1 * 2 * HW32, maxq + 0, maxk + 2,
                 Pz + (size_t)0 * 32 * HW, nullptr, nullptr, PpA,  16, 0, 0, 0, 0 };
    PCfg cA1 = { qT + 0 * 2 * HW32, kT + 2 * 2 * HW32, maxq + 0, maxk + 4,
                 Pz + (size_t)4 * 32 * HW, nullptr, nullptr, PpA2, 16, 0, 0, 0, 0 };
    hipLaunchKernelGGL(pass2p_kernel, dim3(256, 2, 2), dim3(256), 0, stream, cA0, cA1);

    // B: A23 (q2,k3), w = {rz23, c12*rz23}, c12 = sum16 PpA.x ; IC=32 (nit=8)
    PCfg cB = { qT + 1 * 2 * HW32, kT + 2 * 2 * HW32, maxq + 2, maxk + 4,
                Pz + (size_t)2 * 32 * HW, nullptr, PpA, PpB, 8, 0, 0, 16, 0 };
    hipLaunchKernelGGL(pass2p_kernel, dim3(512, 1, 2), dim3(256), 0, stream, cB, cB);

    // C: A32 (q3,k2), w = {c23*rz32, u1*rz32}, c23 = sum32 PpB.x, u1 = sum32 PpB.y
    PCfg cC = { qT + 2 * 2 * HW32, kT + 1 * 2 * HW32, maxq + 4, maxk + 2,
                Pz + (size_t)3 * 32 * HW, PpB, PpB, PpC, 8, 32, 0, 32, 1 };
    hipLaunchKernelGGL(pass2p_kernel, dim3(512, 1, 2), dim3(256), 0, stream, cC, cC);

    // D: A21 (q2,k1), w = {u2*rz21, c12*rz21}, u2 = sum32 PpC.y, c12 = sum16 PpA.x
    PCfg cD = { qT + 1 * 2 * HW32, kT + 0 * 2 * HW32, maxq + 2, maxk + 0,
                Pz + (size_t)1 * 32 * HW, PpC, PpA, PpD, 8, 32, 1, 16, 0 };
    hipLaunchKernelGGL(pass2p_kernel, dim3(512, 1, 2), dim3(256), 0, stream, cD, cD);

    hipLaunchKernelGGL(bcast_kernel, dim3(160), dim3(256), 0, stream, PpA2, PpB, PpC, PpD, out);
}

// Round 11
// 263.391 us; speedup vs baseline: 1.0047x; 1.0047x over previous
//
#include <hip/hip_runtime.h>

typedef unsigned short u16;
typedef u16  u16x8  __attribute__((ext_vector_type(8)));
typedef _Float16 f16x4 __attribute__((ext_vector_type(4)));
typedef _Float16 f16x8 __attribute__((ext_vector_type(8)));
typedef float f32x2 __attribute__((ext_vector_type(2)));
typedef float f32x4 __attribute__((ext_vector_type(4)));

#define HW 4096
#define CIN 256
#define HW32 (HW * 32)
#define L2E 1.4426950408889634f

__device__ __forceinline__ float fexp2(float x) { return __builtin_amdgcn_exp2f(x); }

// ---------------- convert x (fp32->fp16) + channel means; convert W; zero norm slots ----------------
__global__ __launch_bounds__(256) void convert_kernel(const float* x1, const float* x2, const float* x3,
        const float* W1, const float* W2, const float* W3,
        _Float16* xh, _Float16* wh, float* mean, float* maxq, float* maxk) {
    int bx = blockIdx.x; int t = threadIdx.x;
    if (bx < 1536) {
        int xi = bx >> 9, b = (bx >> 8) & 1, c = bx & 255;
        const float* src = (xi == 0 ? x1 : xi == 1 ? x2 : x3) + (size_t)(b * CIN + c) * HW;
        _Float16* dst = xh + ((size_t)((xi * 2 + b) * CIN) + c) * HW;
        float s = 0.f;
        for (int i = t; i < 1024; i += 256) {
            f32x4 v = ((const f32x4*)src)[i];
            s += v[0] + v[1] + v[2] + v[3];
            f16x4 h;
#pragma unroll
            for (int r = 0; r < 4; ++r) h[r] = (_Float16)v[r];
            ((f16x4*)dst)[i] = h;
        }
        __shared__ float red[256];
        red[t] = s; __syncthreads();
        for (int k = 128; k; k >>= 1) { if (t < k) red[t] += red[t + k]; __syncthreads(); }
        if (t == 0) mean[(xi * 2 + b) * CIN + c] = red[0] * (1.f / HW);
    } else {
        int j = bx - 1536;                 // 0..5
        if (j == 0 && t < 12) { if (t < 6) maxq[t] = 0.f; else maxk[t - 6] = 0.f; }
        int widx = j >> 1, half = j & 1;
        const float* wsrc = (widx == 0 ? W1 : widx == 1 ? W2 : W3) + half * 4096;
        _Float16* wdst = wh + widx * 8192 + half * 4096;
        for (int i = t; i < 1024; i += 256) {
            f32x4 v = ((const f32x4*)wsrc)[i];
            f16x4 h;
#pragma unroll
            for (int r = 0; r < 4; ++r) h[r] = (_Float16)v[r];
            ((f16x4*)wdst)[i] = h;
        }
    }
}

// ---- M2 partials: K-split Gram; each wave computes a 32x32 region over a 512-px chunk ----
__global__ __launch_bounds__(256) void m2_kernel(const _Float16* xh, float* Pm2) {
    int xi = blockIdx.y, b = blockIdx.z;
    int xb = xi * 2 + b;
    const _Float16* X = xh + (size_t)xb * CIN * HW;
    int bx = blockIdx.x;              // 0..127 = chunk*16 + blk
    int chunk = bx >> 4, blk = bx & 15;
    int t = threadIdx.x; int wv = t >> 6; int L = t & 63; int m = L & 15; int quad = L >> 4;
    int region = blk * 4 + wv;        // 0..63
    int r1 = (region >> 3) * 32, r2 = (region & 7) * 32;
    int p0 = chunk * 512 + quad * 8;
    const f16x8* A0 = (const f16x8*)(X + (size_t)(r1 + m) * HW + p0);
    const f16x8* A1 = (const f16x8*)(X + (size_t)(r1 + 16 + m) * HW + p0);
    const f16x8* B0 = (const f16x8*)(X + (size_t)(r2 + m) * HW + p0);
    const f16x8* B1 = (const f16x8*)(X + (size_t)(r2 + 16 + m) * HW + p0);
    f32x4 zero = {0, 0, 0, 0};
    f32x4 acc00 = zero, acc01 = zero, acc10 = zero, acc11 = zero;
#pragma unroll 4
    for (int it = 0; it < 16; ++it) {
        f16x8 a0 = A0[it * 4], a1 = A1[it * 4];
        f16x8 b0 = B0[it * 4], b1 = B1[it * 4];
        acc00 = __builtin_amdgcn_mfma_f32_16x16x32_f16(a0, b0, acc00, 0, 0, 0);
        acc01 = __builtin_amdgcn_mfma_f32_16x16x32_f16(a0, b1, acc01, 0, 0, 0);
        acc10 = __builtin_amdgcn_mfma_f32_16x16x32_f16(a1, b0, acc10, 0, 0, 0);
        acc11 = __builtin_amdgcn_mfma_f32_16x16x32_f16(a1, b1, acc11, 0, 0, 0);
    }
    float* dst = Pm2 + ((size_t)chunk * 6 + xb) * 65536;
#pragma unroll
    for (int r = 0; r < 4; ++r) {
        int row0 = (r1 + quad * 4 + r) * 256, row1 = (r1 + 16 + quad * 4 + r) * 256;
        dst[row0 + r2 + m] = acc00[r];
        dst[row0 + r2 + 16 + m] = acc01[r];
        dst[row1 + r2 + m] = acc10[r];
        dst[row1 + r2 + 16 + m] = acc11[r];
    }
}

// ---- combine M2 partials over 8 chunks ----
__global__ __launch_bounds__(256) void m2combine_kernel(const float* Pm2, float* M2) {
    size_t e = (size_t)blockIdx.x * 256 + threadIdx.x;   // 0 .. 6*65536-1
    float s = 0.f;
#pragma unroll
    for (int c = 0; c < 8; ++c) s += Pm2[(size_t)c * 6 * 65536 + e];
    M2[e] = s * (1.f / HW);
}

// ---------------- per-(x,b,o) affine params from stats (q pre-scaled by log2e) ----------------
__global__ __launch_bounds__(256) void stats_kernel(const float* M2, const float* mean,
        const float* W1, const float* W2, const float* W3,
        const float* g1, const float* g2, const float* g3,
        const float* b1, const float* b2, const float* b3, float2* afine) {
    int o = blockIdx.x; int xi = blockIdx.y; int b = blockIdx.z;
    int widx = o >> 5; int oc = o & 31;
    const float* Wp = (widx == 0 ? W1 : widx == 1 ? W2 : W3) + oc * CIN;
    const float* gp = (widx == 0 ? g1 : widx == 1 ? g2 : g3);
    const float* bp = (widx == 0 ? b1 : widx == 1 ? b2 : b3);
    int t = threadIdx.x;
    __shared__ float sW[256];
    __shared__ float red[256];
    sW[t] = Wp[t];
    __syncthreads();
    const float* m2row = M2 + ((size_t)(xi * 2 + b) * CIN + t) * CIN;
    float tv = 0.f;
    const f32x4* r4 = (const f32x4*)m2row;
#pragma unroll 4
    for (int k = 0; k < 64; ++k) {
        f32x4 mv = r4[k];
        const f32x4 wv = *(const f32x4*)&sW[k * 4];
        tv += mv[0] * wv[0] + mv[1] * wv[1] + mv[2] * wv[2] + mv[3] * wv[3];
    }
    red[t] = tv * sW[t]; __syncthreads();
    for (int k = 128; k; k >>= 1) { if (t < k) red[t] += red[t + k]; __syncthreads(); }
    float E2 = red[0]; __syncthreads();
    red[t] = sW[t] * mean[(xi * 2 + b) * CIN + t]; __syncthreads();
    for (int k = 128; k; k >>= 1) { if (t < k) red[t] += red[t + k]; __syncthreads(); }
    if (t == 0) {
        float mu = red[0];
        float var = E2 - mu * mu;
        float rsig = rsqrtf(var + 1e-5f);
        float scale = gp[oc] * rsig;
        float bias = bp[oc] - mu * scale;
        if (widx == 0) { scale *= L2E; bias *= L2E; }   // q carries log2e so S' = S*log2e
        afine[(xi * 2 + b) * 96 + o] = make_float2(scale, bias);
    }
}

// ---- conv + norm + relu: writes qT/kT (fp16), v (fp32 out), and row-norm maxima (atomics) ----
__global__ __launch_bounds__(256) void conv_kernel(const _Float16* xh, const _Float16* wh,
        const float2* afine, _Float16* qT, _Float16* kT, float* out,
        float* maxq, float* maxk) {
    int xi = blockIdx.y, b = blockIdx.z;
    const u16* xb = (const u16*)(xh + (size_t)(xi * 2 + b) * CIN * HW);
    int p0 = blockIdx.x * 64;
    __shared__ u16 lds[32 * 65 * 8];
    __shared__ float smq[4], smk[4];
    int t = threadIdx.x;
    {   // stage x[256][64] into LDS, transposed to 8-channel cells [cblk][f(p)][8c]
        int pc = t & 7, cg = t >> 3;
        u16x8 a[8];
#pragma unroll
        for (int r = 0; r < 8; ++r)
            a[r] = *(const u16x8*)(xb + (size_t)(cg * 8 + r) * HW + p0 + pc * 8);
#pragma unroll
        for (int i = 0; i < 8; ++i) {
            u16x8 d;
#pragma unroll
            for (int r = 0; r < 8; ++r) d[r] = a[r][i];
            int p = pc * 8 + i; int fp = p ^ (p >> 3);
            *(u16x8*)&lds[(cg * 65 + fp) * 8] = d;
        }
    }
    __syncthreads();
    int wv = t >> 6, L = t & 63, m = L & 15, quad = L >> 4;
    int pw0 = wv * 16;
    f16x8 af[8];
    {
        int p = pw0 + m; int fp = p ^ (p >> 3);
#pragma unroll
        for (int k = 0; k < 8; ++k)
            af[k] = *(const f16x8*)&lds[((k * 4 + quad) * 65 + fp) * 8];
    }
    int xb2 = xi * 2 + b;
    float sqq[4] = {0, 0, 0, 0}, sqk[4] = {0, 0, 0, 0};
    for (int ot = 0; ot < 6; ++ot) {
        int o0 = ot * 16; int widx = ot >> 1;
        int o_col = o0 + m;                         // global output channel 0..95
        f32x4 acc = {0, 0, 0, 0};
#pragma unroll
        for (int k = 0; k < 8; ++k) {
            f16x8 bfr = *(const f16x8*)(wh + (size_t)o_col * CIN + k * 32 + quad * 8);
            acc = __builtin_amdgcn_mfma_f32_16x16x32_f16(af[k], bfr, acc, 0, 0, 0);
        }
        float2 afv = afine[xb2 * 96 + o_col];
        f32x4 vals;
#pragma unroll
        for (int r = 0; r < 4; ++r) {
            float v = acc[r] * afv.x + afv.y;
            vals[r] = v > 0.f ? v : 0.f;
        }
        int prow = p0 + pw0 + quad * 4;
        if (widx < 2) {
            _Float16* dst = (widx == 0 ? qT : kT) + (size_t)xb2 * HW32;
            int cc = (o0 & 31) + m;
#pragma unroll
            for (int r = 0; r < 4; ++r)
                dst[(size_t)(prow + r) * 32 + cc] = (_Float16)vals[r];
            if (widx == 0) {
#pragma unroll
                for (int r = 0; r < 4; ++r) sqq[r] += vals[r] * vals[r];
            } else {
#pragma unroll
                for (int r = 0; r < 4; ++r) sqk[r] += vals[r] * vals[r];
            }
        } else {
            float* dst = out + (size_t)(5 + xi) * 262144 + (size_t)b * 131072 + (size_t)(o_col - 64) * HW + prow;
            *(f32x4*)dst = vals;    // fp32 output, 4 consecutive pixels
        }
    }
    // row-norm^2 reduce over 16 channel-lanes, then wave/block max, one atomic per block
#pragma unroll
    for (int msk = 1; msk <= 8; msk <<= 1) {
#pragma unroll
        for (int r = 0; r < 4; ++r) {
            sqq[r] += __shfl_xor(sqq[r], msk);
            sqk[r] += __shfl_xor(sqk[r], msk);
        }
    }
    float nq = fmaxf(fmaxf(sqq[0], sqq[1]), fmaxf(sqq[2], sqq[3]));
    float nk = fmaxf(fmaxf(sqk[0], sqk[1]), fmaxf(sqk[2], sqk[3]));
    nq = fmaxf(nq, __shfl_xor(nq, 16)); nq = fmaxf(nq, __shfl_xor(nq, 32));
    nk = fmaxf(nk, __shfl_xor(nk, 16)); nk = fmaxf(nk, __shfl_xor(nk, 32));
    if (L == 0) { smq[wv] = nq; smk[wv] = nk; }
    __syncthreads();
    if (t == 0) {
        float bq = fmaxf(fmaxf(smq[0], smq[1]), fmaxf(smq[2], smq[3]));
        float bk = fmaxf(fmaxf(smk[0], smk[1]), fmaxf(smk[2], smk[3]));
        atomicMax((unsigned*)&maxq[xb2], __float_as_uint(bq));   // nonneg floats: uint order == float order
        atomicMax((unsigned*)&maxk[xb2], __float_as_uint(bk));
    }
}

// ---- Z-sweep (single pass, constant shift): 8 j-chunks x 32 j-iters/wave ----
__global__ __launch_bounds__(256) void zsweep_kernel(const _Float16* qT, const _Float16* kT,
        const float* maxq, const float* maxk, float* Pz) {
    const int qxA[5] = {0, 1, 1, 2, 0};   // mats: A12 A21 A23 A32 A13
    const int kxA[5] = {1, 0, 2, 1, 2};
    int mat = blockIdx.y, b = blockIdx.z;
    const _Float16* qb = qT + (size_t)(qxA[mat] * 2 + b) * HW32;
    const _Float16* kb = kT + (size_t)(kxA[mat] * 2 + b) * HW32;
    float Cg = sqrtf(maxq[qxA[mat] * 2 + b]) * sqrtf(maxk[kxA[mat] * 2 + b]);  // log2-domain (q scaled by L2E)
    int bx = blockIdx.x;                 // 16 qblk x 8 jc
    int jc = bx & 7, qblk = bx >> 3;
    int t = threadIdx.x; int wv = t >> 6; int L = t & 63; int m = L & 15; int quad = L >> 4;
    int i0 = qblk * 256 + wv * 64;       // wave covers 64 q rows (4 tiles)
    f16x8 a[4];
#pragma unroll
    for (int tt = 0; tt < 4; ++tt)
        a[tt] = *(const f16x8*)(qb + (size_t)(i0 + tt * 16 + m) * 32 + quad * 8);
    const f16x8* kp = (const f16x8*)(kb + m * 32 + quad * 8) + (size_t)jc * (32 * 64);
    f32x4 negC = {-Cg, -Cg, -Cg, -Cg};
    f32x4 zero = {0.f, 0.f, 0.f, 0.f};
    f32x4 z[4] = {zero, zero, zero, zero};
#pragma unroll 4
    for (int j = 0; j < 32; ++j) {
        f16x8 bf = kp[j * 64];
#pragma unroll
        for (int tt = 0; tt < 4; ++tt) {
            f32x4 d = __builtin_amdgcn_mfma_f32_16x16x32_f16(a[tt], bf, negC, 0, 0, 0);
            f32x4 e = {fexp2(d[0]), fexp2(d[1]), fexp2(d[2]), fexp2(d[3])};
            z[tt] = z[tt] + e;           // vector add -> v_pk_add_f32
        }
    }
#pragma unroll
    for (int tt = 0; tt < 4; ++tt)
#pragma unroll
        for (int msk = 1; msk <= 8; msk <<= 1) {
            z[tt][0] += __shfl_xor(z[tt][0], msk); z[tt][1] += __shfl_xor(z[tt][1], msk);
            z[tt][2] += __shfl_xor(z[tt][2], msk); z[tt][3] += __shfl_xor(z[tt][3], msk);
        }
    if (m == 0) {
        int mb = mat * 2 + b;
#pragma unroll
        for (int tt = 0; tt < 4; ++tt) {
            int row = i0 + tt * 16 + quad * 4;
#pragma unroll
            for (int r = 0; r < 4; ++r)
                Pz[((size_t)mb * 8 + jc) * HW + row + r] = z[tt][r];
        }
    }
}

// ---- pass2, i-chunked, 4 j-tiles/wave; prologue builds its own weights from Pz + partials ----
struct PCfg {
    const _Float16* qb; const _Float16* kb;   // bases covering 2 batches
    const float* mq; const float* mk;         // per-batch shift factors (squared norms)
    const float* PzR;                         // Pz partials for THIS sweep's own mat (+b*8*HW inside)
    const float2* w1src;                      // partials for w.x multiplier (null -> w.x = rz)
    const float2* w2src;                      // partials for w.y multiplier (null -> single-weight)
    float2* Pp;                               // [(ic*2+b)*HW + j]
    int nit;                                  // i-iters per chunk (chunk = nit*16 rows)
    int ic1, comp1, ic2, comp2;               // chunk counts + component (0=.x,1=.y)
};

__global__ __launch_bounds__(256) void pass2p_kernel(PCfg c0, PCfg c1) {
    PCfg c = (blockIdx.y == 0) ? c0 : c1;
    int b = blockIdx.z;
    int bx = blockIdx.x; int jb = bx & 15; int ic = bx >> 4;
    const _Float16* qb = c.qb + (size_t)b * HW32;
    const _Float16* kb = c.kb + (size_t)b * HW32;
    float Cg = sqrtf(c.mq[b]) * sqrtf(c.mk[b]);
    int t = threadIdx.x; int wv = t >> 6; int L = t & 63; int m = L & 15; int quad = L >> 4;
    int ibase = ic * (c.nit * 16);
    int rows = c.nit * 16;                    // 128 or 256
    __shared__ float2 wlds[256];
    {   // prologue: weights for this block's i-rows (identical arithmetic to old prep kernels)
        for (int r = t; r < rows; r += 256) {
            int i = ibase + r;
            const float* pz = c.PzR + (size_t)b * (8 * HW) + i;
            float Z = 0.f;
#pragma unroll
            for (int cc = 0; cc < 8; ++cc) Z += pz[cc * HW];
            float rz = 1.0f / Z;
            float wx, wy = 0.f;
            if (c.w1src) {
                float s = 0.f;
                for (int cc = 0; cc < c.ic1; ++cc) {
                    float2 p = c.w1src[((size_t)cc * 2 + b) * HW + i];
                    s += c.comp1 ? p.y : p.x;
                }
                wx = s * rz;
            } else wx = rz;
            if (c.w2src) {
                float s = 0.f;
                for (int cc = 0; cc < c.ic2; ++cc) {
                    float2 p = c.w2src[((size_t)cc * 2 + b) * HW + i];
                    s += c.comp2 ? p.y : p.x;
                }
                wy = s * rz;
            }
            wlds[r] = make_float2(wx, wy);
        }
    }
    __syncthreads();
    int j0 = jb * 256 + wv * 64;         // wave covers 64 j columns (4 tiles)
    f16x8 bf[4];
#pragma unroll
    for (int tt = 0; tt < 4; ++tt)
        bf[tt] = *(const f16x8*)(kb + (size_t)(j0 + tt * 16 + m) * 32 + quad * 8);
    f32x4 negC = {-Cg, -Cg, -Cg, -Cg};
    f32x2 acc[4] = {{0, 0}, {0, 0}, {0, 0}, {0, 0}};
    int dual = (c.w2src != nullptr);
    if (dual) {
#pragma unroll 4
        for (int it = 0; it < c.nit; ++it) {
            int i0 = ibase + it * 16;
            f16x8 av = *(const f16x8*)(qb + (size_t)(i0 + m) * 32 + quad * 8);
            const float2* wr = &wlds[it * 16 + quad * 4];
            f32x2 w0 = {wr[0].x, wr[0].y}, w1 = {wr[1].x, wr[1].y};
            f32x2 w2 = {wr[2].x, wr[2].y}, w3 = {wr[3].x, wr[3].y};
#pragma unroll
            for (int tt = 0; tt < 4; ++tt) {
                f32x4 d = __builtin_amdgcn_mfma_f32_16x16x32_f16(av, bf[tt], negC, 0, 0, 0);
                float e0 = fexp2(d[0]), e1 = fexp2(d[1]), e2 = fexp2(d[2]), e3 = fexp2(d[3]);
                acc[tt] += (f32x2){e0, e0} * w0;   // v_pk_fma_f32
                acc[tt] += (f32x2){e1, e1} * w1;
                acc[tt] += (f32x2){e2, e2} * w2;
                acc[tt] += (f32x2){e3, e3} * w3;
            }
        }
    } else {
#pragma unroll 4
        for (int it = 0; it < c.nit; ++it) {
            int i0 = ibase + it * 16;
            f16x8 av = *(const f16x8*)(qb + (size_t)(i0 + m) * 32 + quad * 8);
            const float2* wr = &wlds[it * 16 + quad * 4];
            float w0 = wr[0].x, w1 = wr[1].x, w2 = wr[2].x, w3 = wr[3].x;
#pragma unroll
            for (int tt = 0; tt < 4; ++tt) {
                f32x4 d = __builtin_amdgcn_mfma_f32_16x16x32_f16(av, bf[tt], negC, 0, 0, 0);
                float e0 = fexp2(d[0]), e1 = fexp2(d[1]), e2 = fexp2(d[2]), e3 = fexp2(d[3]);
                acc[tt][0] += e0 * w0 + e1 * w1 + e2 * w2 + e3 * w3;
            }
        }
    }
#pragma unroll
    for (int tt = 0; tt < 4; ++tt) {
        acc[tt][0] += __shfl_xor(acc[tt][0], 16); acc[tt][0] += __shfl_xor(acc[tt][0], 32);
        acc[tt][1] += __shfl_xor(acc[tt][1], 16); acc[tt][1] += __shfl_xor(acc[tt][1], 32);
    }
    if (quad == 0) {
        float2* dst = c.Pp + ((size_t)ic * 2 + b) * HW;
#pragma unroll
        for (int tt = 0; tt < 4; ++tt)
            dst[j0 + tt * 16 + m] = make_float2(acc[tt][0], acc[tt][1]);
    }
}

// ---- bcast: sum partials for the 5 output vectors, broadcast to fp32 [b,32,hw] ----
__global__ __launch_bounds__(256) void bcast_kernel(const float2* PpA2, const float2* PpB,
        const float2* PpC, const float2* PpD, float* out) {
    int bx = blockIdx.x;              // 0..159: (s*2+b)*16 + jstrip
    int sb = bx >> 4; int s = sb >> 1; int b = sb & 1; int js = bx & 15;
    int j = js * 256 + threadIdx.x;
    float v = 0.f;
    if (s == 0)      { for (int ic = 0; ic < 32; ++ic) v += PpD[((size_t)ic * 2 + b) * HW + j].x; }
    else if (s == 1) { for (int ic = 0; ic < 32; ++ic) v += PpD[((size_t)ic * 2 + b) * HW + j].y; }
    else if (s == 2) { for (int ic = 0; ic < 32; ++ic) v += PpC[((size_t)ic * 2 + b) * HW + j].x; }
    else if (s == 3) { for (int ic = 0; ic < 32; ++ic) v += PpB[((size_t)ic * 2 + b) * HW + j].y; }
    else             { for (int ic = 0; ic < 16; ++ic) v += PpA2[((size_t)ic * 2 + b) * HW + j].x; }
    float* dst = out + ((size_t)(s * 2 + b) * 32) * HW + j;
#pragma unroll
    for (int c = 0; c < 32; ++c) dst[(size_t)c * HW] = v;
}

extern "C" void kernel_launch(void* const* d_in, const int* in_sizes, int n_in,
                              void* d_out, int out_size, void* d_ws, size_t ws_size,
                              hipStream_t stream) {
    (void)in_sizes; (void)n_in; (void)out_size; (void)ws_size;
    const float* x1 = (const float*)d_in[0];
    const float* x2 = (const float*)d_in[1];
    const float* x3 = (const float*)d_in[2];
    const float* W1 = (const float*)d_in[3];
    const float* g1 = (const float*)d_in[4];
    const float* b1 = (const float*)d_in[5];
    const float* W2 = (const float*)d_in[6];
    const float* g2 = (const float*)d_in[7];
    const float* b2 = (const float*)d_in[8];
    const float* W3 = (const float*)d_in[9];
    const float* g3 = (const float*)d_in[10];
    const float* b3 = (const float*)d_in[11];
    float* out = (float*)d_out;      // reference outputs are float32

    char* w = (char*)d_ws;
    _Float16* xh    = (_Float16*)(w);                    // 12,582,912
    _Float16* wh    = (_Float16*)(w + 12582912);         //     49,152
    float*    mean  = (float*)(w + 12632064);            //      6,144
    float*    M2    = (float*)(w + 12638208);            //  1,572,864
    float2*   afine = (float2*)(w + 14211072);           //      4,608
    _Float16* qT    = (_Float16*)(w + 14215680);         //  1,572,864
    _Float16* kT    = (_Float16*)(w + 15788544);         //  1,572,864
    float*    maxq  = (float*)(w + 17525248);            //         64 (squared norms)
    float*    maxk  = (float*)(w + 17525312);            //         64
    float*    Pz    = (float*)(w + 18213376);            //  1,310,720 (10 mb x 8 chunks x HW)
    float2*   PpA   = (float2*)(w + 23456256);           //  2,097,152 (A12: 16 ch; A13: 16 ch)
    float2*   PpB   = (float2*)(w + 25553408);           //  2,097,152
    float2*   PpC   = (float2*)(w + 27650560);           //  2,097,152
    float2*   PpD   = (float2*)(w + 29747712);           //  2,097,152
    // Pm2 overlays Pz/PpA/PpB/PpC (disjoint lifetime: consumed by m2combine before zsweep runs)
    float*    Pm2   = (float*)(w + 18213376);            // 12,582,912 (8 chunks x 6 x 256x256 f32)
    float2*   PpA2  = PpA + 16 * 2 * HW;                 // A13 partial region

    hipLaunchKernelGGL(convert_kernel, dim3(1542), dim3(256), 0, stream,
                       x1, x2, x3, W1, W2, W3, xh, wh, mean, maxq, maxk);
    hipLaunchKernelGGL(m2_kernel, dim3(128, 3, 2), dim3(256), 0, stream, xh, Pm2);
    hipLaunchKernelGGL(m2combine_kernel, dim3(1536), dim3(256), 0, stream, Pm2, M2);
    hipLaunchKernelGGL(stats_kernel, dim3(96, 3, 2), dim3(256), 0, stream,
                       M2, mean, W1, W2, W3, g1, g2, g3, b1, b2, b3, afine);
    hipLaunchKernelGGL(conv_kernel, dim3(64, 3, 2), dim3(256), 0, stream,
                       xh, wh, afine, qT, kT, out, maxq, maxk);
    hipLaunchKernelGGL(zsweep_kernel, dim3(128, 5, 2), dim3(256), 0, stream, qT, kT, maxq, maxk, Pz);

    // mats: 0:A12(q1,k2) 1:A21(q2,k1) 2:A23(q2,k3) 3:A32(q3,k2) 4:A13(q1,k3)
    // A-pair: A12 (w={rz}) and A13 (w={rz}); IC=16 (nit=16), single-weight
    PCfg cA0 = { qT + 0 * 2 * HW32, kT + 1 * 2 * HW32, maxq + 0, maxk + 2,
                 Pz + (size_t)0 * 16 * HW, nullptr, nullptr, PpA,  16, 0, 0, 0, 0 };
    PCfg cA1 = { qT + 0 * 2 * HW32, kT + 2 * 2 * HW32, maxq + 0, maxk + 4,
                 Pz + (size_t)4 * 16 * HW, nullptr, nullptr, PpA2, 16, 0, 0, 0, 0 };
    hipLaunchKernelGGL(pass2p_kernel, dim3(256, 2, 2), dim3(256), 0, stream, cA0, cA1);

    // B: A23 (q2,k3), w = {rz23, c12*rz23}, c12 = sum16 PpA.x ; IC=32 (nit=8)
    PCfg cB = { qT + 1 * 2 * HW32, kT + 2 * 2 * HW32, maxq + 2, maxk + 4,
                Pz + (size_t)2 * 16 * HW, nullptr, PpA, PpB, 8, 0, 0, 16, 0 };
    hipLaunchKernelGGL(pass2p_kernel, dim3(512, 1, 2), dim3(256), 0, stream, cB, cB);

    // C: A32 (q3,k2), w = {c23*rz32, u1*rz32}, c23 = sum32 PpB.x, u1 = sum32 PpB.y
    PCfg cC = { qT + 2 * 2 * HW32, kT + 1 * 2 * HW32, maxq + 4, maxk + 2,
                Pz + (size_t)3 * 16 * HW, PpB, PpB, PpC, 8, 32, 0, 32, 1 };
    hipLaunchKernelGGL(pass2p_kernel, dim3(512, 1, 2), dim3(256), 0, stream, cC, cC);

    // D: A21 (q2,k1), w = {u2*rz21, c12*rz21}, u2 = sum32 PpC.y, c12 = sum16 PpA.x
    PCfg cD = { qT + 1 * 2 * HW32, kT + 0 * 2 * HW32, maxq + 2, maxk + 0,
                Pz + (size_t)1 * 16 * HW, PpC, PpA, PpD, 8, 32, 1, 16, 0 };
    hipLaunchKernelGGL(pass2p_kernel, dim3(512, 1, 2), dim3(256), 0, stream, cD, cD);

    hipLaunchKernelGGL(bcast_kernel, dim3(160), dim3(256), 0, stream, PpA2, PpB, PpC, PpD, out);
}